// Round 5
// baseline (91.870 us; speedup 1.0000x reference)
//
#include <hip/hip_runtime.h>

// B=8, T_dec=64, T_enc=512, H=512.  bf16-MFMA pipeline, 4 launches.
// All MFMA operands in FRAGMENT-MAJOR layout (16-row x 32-k tile = 64 lanes'
// short8 fragments contiguous, 1 KB) -> every operand load is one coalesced
// dwordx4 per lane.
//   K1 fused_cast: W->Wd_f/We_f, dec->dec_f, enc->enc_f + encT_f, zero S12
//   K2 gemm1:      part = [dec;enc] @ {Wd|We}^T
//                  dec blocks: part_bf (plain) + uv_f = exp(part)
//                  enc blocks: uv_f = exp(part+bias)  AND  S1/S2 epilogue:
//                    S1[b,o] += sum_j enc[b,j,o];  S2[b,o] += sum_j part*enc
//                    (enc fp32 tile re-read here, part from LDS — kills the
//                     separate s1s2 pass and its 12 MB of HBM re-reads)
//   K3 lse:        lse_f = log(U.V^T)  (split-K x4, LDS reduce)
//   K4 final:      out = (dec_part+bias)*S1 + S2 - lse @ encT
// No max-subtraction (|logit|<=~14, exp safe in fp32). absmax ~4 < 14.8 thr.

namespace {
constexpr int kH  = 512;
constexpr int kTD = 64;
constexpr int kTE = 512;
constexpr int kB  = 8;
constexpr int kRD = kB * kTD;          // 512
constexpr int kRE = kB * kTE;          // 4096
}

typedef __attribute__((ext_vector_type(8))) short short8;   // 8 x bf16
typedef __attribute__((ext_vector_type(4))) float floatx4;  // MFMA C/D

__device__ __forceinline__ unsigned short f2bf(float x) {
    unsigned u = __float_as_uint(x);
    u += 0x7fffu + ((u >> 16) & 1u);          // RNE
    return (unsigned short)(u >> 16);
}
__device__ __forceinline__ float bf2f(unsigned short h) {
    return __uint_as_float(((unsigned)h) << 16);
}
__device__ __forceinline__ size_t fragTile(int rtile, int kt) {
    return ((size_t)rtile * 16 + kt) * 512;   // ushort index of tile base
}
__device__ __forceinline__ short8 pack8(float4 a, float4 b) {
    short8 r;
    r[0] = (short)f2bf(a.x); r[1] = (short)f2bf(a.y);
    r[2] = (short)f2bf(a.z); r[3] = (short)f2bf(a.w);
    r[4] = (short)f2bf(b.x); r[5] = (short)f2bf(b.y);
    r[6] = (short)f2bf(b.z); r[7] = (short)f2bf(b.w);
    return r;
}

// ---------------------------------------------------------------------------
// K1: blocks [0,256): W -> Wd_f/We_f (frag); blocks [0,32) also zero S12.
//     blocks [256,384): dec -> dec_f (frag)
//     blocks [384,1408): enc -> enc_f (frag) + encT_f (frag, LDS transpose)
// ---------------------------------------------------------------------------
__global__ __launch_bounds__(256) void fused_cast(
    const float* __restrict__ W, const float* __restrict__ dec,
    const float* __restrict__ enc,
    unsigned short* __restrict__ Wd_f, unsigned short* __restrict__ We_f,
    unsigned short* __restrict__ dec_f,
    unsigned short* __restrict__ enc_f, unsigned short* __restrict__ encT_f,
    float* __restrict__ S12)
{
    const int blk = blockIdx.x, t = threadIdx.x;
    const int w = t >> 6, l = t & 63;
    const int lr = l & 15, lc = l >> 4;
    if (blk < 256) {
        const int gw = blk * 4 + w;               // [0,1024)
        const int sel = gw >> 9, rem = gw & 511;
        const int ot = rem >> 4, kt = rem & 15;
        const int o = ot * 16 + lr;
        const float* src = W + (size_t)o * 1024 + sel * 512 + kt * 32 + lc * 8;
        const float4 v0 = *(const float4*)src;
        const float4 v1 = *(const float4*)(src + 4);
        unsigned short* dst = (sel ? We_f : Wd_f) + fragTile(ot, kt) + l * 8;
        *(short8*)dst = pack8(v0, v1);
        if (blk < 32) S12[blk * 256 + t] = 0.f;   // no K1 atomics -> safe
    } else if (blk < 384) {
        const int gw = (blk - 256) * 4 + w;       // [0,512)
        const int rt = gw >> 4, kt = gw & 15;
        const int r = rt * 16 + lr;
        const float* src = dec + (size_t)r * kH + kt * 32 + lc * 8;
        const float4 v0 = *(const float4*)src;
        const float4 v1 = *(const float4*)(src + 4);
        *(short8*)(dec_f + fragTile(rt, kt) + l * 8) = pack8(v0, v1);
    } else {
        __shared__ unsigned short s[64][36];      // 64 j x 32 d (+pad)
        const int e = blk - 384;                  // [0,1024)
        const int kt = e & 15, jt = (e >> 4) & 7, b = e >> 7;
        const int j0 = jt * 64, d0 = kt * 32;
        const int jl = w * 16 + lr;               // local j (0..63)
        const float* src = enc + ((size_t)(b * kTE + j0 + jl)) * kH + d0 + lc * 8;
        const float4 v0 = *(const float4*)src;
        const float4 v1 = *(const float4*)(src + 4);
        const short8 p = pack8(v0, v1);
        *(short8*)(enc_f + fragTile(b * 32 + jt * 4 + w, kt) + l * 8) = p;
#pragma unroll
        for (int i = 0; i < 8; ++i) s[jl][lc * 8 + i] = (unsigned short)p[i];
        __syncthreads();
        const int dt = w >> 1, jc = w & 1;        // wave -> one encT frag tile
        const int dl = dt * 16 + lr;              // local d (0..31)
        const int j8 = jc * 32 + lc * 8;          // local j chunk
        short8 v;
#pragma unroll
        for (int i = 0; i < 8; ++i) v[i] = (short)s[j8 + i][dl];
        *(short8*)(encT_f + fragTile(b * 32 + kt * 2 + dt, jt * 2 + jc) + l * 8) = v;
    }
}

// ---------------------------------------------------------------------------
// K2: gemm1.  576 blocks; block = 64x64 tile; wave = 32x32 quadrant.
// M = 4608 (rows 0..511 dec, 512.. enc), N = 512, K = 512.
// dec blocks: part_bf (plain) + uv_f.   enc blocks: uv_f + S1/S2 reduction.
// ---------------------------------------------------------------------------
__global__ __launch_bounds__(256) void gemm1(
    const unsigned short* __restrict__ enc_f,
    const unsigned short* __restrict__ dec_f,
    const unsigned short* __restrict__ Wd_f,
    const unsigned short* __restrict__ We_f,
    const float* __restrict__ bias,
    const float* __restrict__ enc,
    unsigned short* __restrict__ part_bf, unsigned short* __restrict__ uv_f,
    float* __restrict__ S12)
{
    __shared__ float As[64][68];
    __shared__ float r1[16][68];
    __shared__ float r2[16][68];
    const int tile = blockIdx.x;
    const int ns = tile & 7, ms = tile >> 3;
    const int t = threadIdx.x, w = t >> 6, l = t & 63;
    const int qm = w >> 1, qn = w & 1;
    const bool isenc = (ms >= 8);
    const unsigned short* A = isenc ? enc_f : dec_f;
    const unsigned short* Bw = isenc ? We_f : Wd_f;
    const int art = (isenc ? (ms - 8) : ms) * 4 + qm * 2;
    const int brt = ns * 4 + qn * 2;

    floatx4 acc[2][2];
#pragma unroll
    for (int m = 0; m < 2; ++m)
#pragma unroll
        for (int n = 0; n < 2; ++n) acc[m][n] = (floatx4){0.f, 0.f, 0.f, 0.f};

    for (int kt = 0; kt < 16; ++kt) {
        short8 af[2], bfr[2];
#pragma unroll
        for (int m = 0; m < 2; ++m)
            af[m] = *(const short8*)(A + fragTile(art + m, kt) + l * 8);
#pragma unroll
        for (int n = 0; n < 2; ++n)
            bfr[n] = *(const short8*)(Bw + fragTile(brt + n, kt) + l * 8);
#pragma unroll
        for (int m = 0; m < 2; ++m)
#pragma unroll
            for (int n = 0; n < 2; ++n)
                acc[m][n] = __builtin_amdgcn_mfma_f32_16x16x32_bf16(af[m], bfr[n], acc[m][n], 0, 0, 0);
    }

    const int lr = l & 15, lq = l >> 4;
#pragma unroll
    for (int m = 0; m < 2; ++m)
#pragma unroll
        for (int n = 0; n < 2; ++n)
#pragma unroll
            for (int r = 0; r < 4; ++r)
                As[qm * 32 + m * 16 + lq * 4 + r][qn * 32 + n * 16 + lr] = acc[m][n][r];
    __syncthreads();

    const int rowbase = ms * 64, colbase = ns * 64;
    if (!isenc) {
        // part_bf plain: 8 rows x 128 B per wave-store, fully coalesced
#pragma unroll
        for (int h = 0; h < 2; ++h) {
            const int a = h * 256 + t;
            const int row = a >> 3, cc = (a & 7) * 8;
            const float4 v0 = *(const float4*)&As[row][cc];
            const float4 v1 = *(const float4*)&As[row][cc + 4];
            *(short8*)(part_bf + (size_t)(rowbase + row) * kH + colbase + cc) = pack8(v0, v1);
        }
    }
    // uv_f frag: slot s -> (rt, kc, fl)
#pragma unroll
    for (int h = 0; h < 2; ++h) {
        const int s = h * 256 + t;
        const int rt = s >> 7, kc = (s >> 6) & 1, fl = s & 63;
        const int row = rt * 16 + (fl & 15);
        const int col = kc * 32 + (fl >> 4) * 8;
        const float4 v0 = *(const float4*)&As[row][col];
        const float4 v1 = *(const float4*)&As[row][col + 4];
        float4 b0 = make_float4(0.f, 0.f, 0.f, 0.f), b1 = b0;
        if (isenc) {
            b0 = *(const float4*)(bias + colbase + col);
            b1 = *(const float4*)(bias + colbase + col + 4);
        }
        short8 u;
        u[0] = (short)f2bf(__expf(v0.x + b0.x));
        u[1] = (short)f2bf(__expf(v0.y + b0.y));
        u[2] = (short)f2bf(__expf(v0.z + b0.z));
        u[3] = (short)f2bf(__expf(v0.w + b0.w));
        u[4] = (short)f2bf(__expf(v1.x + b1.x));
        u[5] = (short)f2bf(__expf(v1.y + b1.y));
        u[6] = (short)f2bf(__expf(v1.z + b1.z));
        u[7] = (short)f2bf(__expf(v1.w + b1.w));
        *(short8*)(uv_f + fragTile(ms * 4 + rt, ns * 2 + kc) + fl * 8) = u;
    }
    if (isenc) {
        // S1/S2 over this block's 64 j x 64 o tile.  part is in As (fp32).
        const int b = (ms - 8) >> 3;
        const int jbase = ((ms - 8) & 7) * 64;
        const int o4 = (t & 15) * 4, jg = t >> 4;    // 16 j-groups x 4 j
        float4 s1p = make_float4(0.f, 0.f, 0.f, 0.f);
        float4 s2p = make_float4(0.f, 0.f, 0.f, 0.f);
#pragma unroll
        for (int jj = 0; jj < 4; ++jj) {
            const int j = jg * 4 + jj;
            const float4 ev = *(const float4*)(
                enc + ((size_t)(b * kTE + jbase + j)) * kH + colbase + o4);
            const float4 pv = *(const float4*)&As[j][o4];
            s1p.x += ev.x; s1p.y += ev.y; s1p.z += ev.z; s1p.w += ev.w;
            s2p.x = fmaf(pv.x, ev.x, s2p.x);
            s2p.y = fmaf(pv.y, ev.y, s2p.y);
            s2p.z = fmaf(pv.z, ev.z, s2p.z);
            s2p.w = fmaf(pv.w, ev.w, s2p.w);
        }
        *(float4*)&r1[jg][o4] = s1p;
        *(float4*)&r2[jg][o4] = s2p;
        __syncthreads();
        if (t < 64) {
            float a1 = 0.f, a2 = 0.f;
#pragma unroll
            for (int g = 0; g < 16; ++g) { a1 += r1[g][t]; a2 += r2[g][t]; }
            atomicAdd(&S12[b * kH + colbase + t], a1);
            atomicAdd(&S12[4096 + b * kH + colbase + t], a2);
        }
    }
}

// ---------------------------------------------------------------------------
// K3: lse.  256 blocks; tile 16(i) x 64(j), 4 waves split K=512 4-ways,
// LDS reduce, log epilogue -> lse_f (frag layout).
// ---------------------------------------------------------------------------
__global__ __launch_bounds__(256) void lse_k(
    const unsigned short* __restrict__ uv_f, unsigned short* __restrict__ lse_f)
{
    __shared__ float red[4][16][68];
    const int blk = blockIdx.x, t = threadIdx.x;
    const int b = blk >> 5, rem = blk & 31;
    const int it = rem >> 3, jt = rem & 7;
    const int w = t >> 6, l = t & 63;
    const int art = b * 4 + it;               // U rows (dec region)
    const int vrt0 = 32 + b * 32 + jt * 4;    // V rows (enc region)

    floatx4 acc[4];
#pragma unroll
    for (int n = 0; n < 4; ++n) acc[n] = (floatx4){0.f, 0.f, 0.f, 0.f};
#pragma unroll
    for (int kk = 0; kk < 4; ++kk) {
        const int kt = w * 4 + kk;
        const short8 af = *(const short8*)(uv_f + fragTile(art, kt) + l * 8);
#pragma unroll
        for (int n = 0; n < 4; ++n)
            acc[n] = __builtin_amdgcn_mfma_f32_16x16x32_bf16(
                af, *(const short8*)(uv_f + fragTile(vrt0 + n, kt) + l * 8), acc[n], 0, 0, 0);
    }
    const int lr = l & 15, lq = l >> 4;
#pragma unroll
    for (int n = 0; n < 4; ++n)
#pragma unroll
        for (int r = 0; r < 4; ++r)
            red[w][lq * 4 + r][n * 16 + lr] = acc[n][r];
    __syncthreads();
    const int s = t >> 1, h = t & 1;
    const int kc = s >> 6, fl = s & 63;
    const int i = fl & 15;
    const int j = kc * 32 + (fl >> 4) * 8 + h * 4;
    float4 sum = *(const float4*)&red[0][i][j];
    const float4 s1 = *(const float4*)&red[1][i][j];
    const float4 s2 = *(const float4*)&red[2][i][j];
    const float4 s3 = *(const float4*)&red[3][i][j];
    sum.x += s1.x + s2.x + s3.x; sum.y += s1.y + s2.y + s3.y;
    sum.z += s1.z + s2.z + s3.z; sum.w += s1.w + s2.w + s3.w;
    ushort4 o;
    o.x = f2bf(__logf(sum.x)); o.y = f2bf(__logf(sum.y));
    o.z = f2bf(__logf(sum.z)); o.w = f2bf(__logf(sum.w));
    *(ushort4*)(lse_f + fragTile(b * 4 + it, jt * 2 + kc) + fl * 8 + h * 4) = o;
}

// ---------------------------------------------------------------------------
// K4: final.  256 blocks; tile 16(i) x 64(d), 4 waves split K(j)=512 4-ways.
// out[b,i,d] = (dec_part+bias)*S1 + S2 - sum_j lse[b,i,j]*encT[b,d,j]
// ---------------------------------------------------------------------------
__global__ __launch_bounds__(256) void final_k(
    const unsigned short* __restrict__ lse_f,
    const unsigned short* __restrict__ encT_f,
    const unsigned short* __restrict__ part_bf,
    const float* __restrict__ bias,
    const float* __restrict__ S12,
    float* __restrict__ out)
{
    __shared__ float red[4][16][68];
    const int blk = blockIdx.x, t = threadIdx.x;
    const int b = blk >> 5, rem = blk & 31;
    const int it = rem >> 3, dt = rem & 7;
    const int w = t >> 6, l = t & 63;
    const int art = b * 4 + it;                   // lse rows
    const int brt0 = b * 32 + dt * 4;             // encT rows (d)

    floatx4 acc[4];
#pragma unroll
    for (int n = 0; n < 4; ++n) acc[n] = (floatx4){0.f, 0.f, 0.f, 0.f};
#pragma unroll
    for (int kk = 0; kk < 4; ++kk) {
        const int kt = w * 4 + kk;
        const short8 af = *(const short8*)(lse_f + fragTile(art, kt) + l * 8);
#pragma unroll
        for (int n = 0; n < 4; ++n)
            acc[n] = __builtin_amdgcn_mfma_f32_16x16x32_bf16(
                af, *(const short8*)(encT_f + fragTile(brt0 + n, kt) + l * 8), acc[n], 0, 0, 0);
    }
    const int lr = l & 15, lq = l >> 4;
#pragma unroll
    for (int n = 0; n < 4; ++n)
#pragma unroll
        for (int r = 0; r < 4; ++r)
            red[w][lq * 4 + r][n * 16 + lr] = acc[n][r];
    __syncthreads();
    const int i = t >> 4, d0 = (t & 15) * 4;
    float4 m = *(const float4*)&red[0][i][d0];
    const float4 m1 = *(const float4*)&red[1][i][d0];
    const float4 m2 = *(const float4*)&red[2][i][d0];
    const float4 m3 = *(const float4*)&red[3][i][d0];
    m.x += m1.x + m2.x + m3.x; m.y += m1.y + m2.y + m3.y;
    m.z += m1.z + m2.z + m3.z; m.w += m1.w + m2.w + m3.w;

    const int gd = dt * 64 + d0;
    const float4 s1 = *(const float4*)(S12 + b * kH + gd);
    const float4 s2 = *(const float4*)(S12 + 4096 + b * kH + gd);
    const float4 bi = *(const float4*)(bias + gd);
    const int row = b * kTD + it * 16 + i;
    const ushort4 dp = *(const ushort4*)(part_bf + (size_t)row * kH + gd);
    float4 o;
    o.x = fmaf(bf2f(dp.x) + bi.x, s1.x, s2.x) - m.x;
    o.y = fmaf(bf2f(dp.y) + bi.y, s1.y, s2.y) - m.y;
    o.z = fmaf(bf2f(dp.z) + bi.z, s1.z, s2.z) - m.z;
    o.w = fmaf(bf2f(dp.w) + bi.w, s1.w, s2.w) - m.w;
    *(float4*)(out + (size_t)row * kH + gd) = o;
}

// ---------------------------------------------------------------------------
extern "C" void kernel_launch(void* const* d_in, const int* in_sizes, int n_in,
                              void* d_out, int out_size, void* d_ws, size_t ws_size,
                              hipStream_t stream)
{
    (void)in_sizes; (void)n_in; (void)out_size; (void)ws_size;
    const float* enc  = (const float*)d_in[0];
    const float* dec  = (const float*)d_in[1];
    const float* W    = (const float*)d_in[2];
    const float* bias = (const float*)d_in[3];
    float* out = (float*)d_out;

    char* base = (char*)d_ws;
    unsigned short* part_bf = (unsigned short*)(base);              //   524,288 (dec rows only)
    unsigned short* uv_f    = (unsigned short*)(base + 4718592);    // 4,718,592
    unsigned short* enc_f   = (unsigned short*)(base + 9437184);    // 4,194,304
    unsigned short* encT_f  = (unsigned short*)(base + 13631488);   // 4,194,304
    unsigned short* dec_f   = (unsigned short*)(base + 17825792);   //   524,288
    unsigned short* Wd_f    = (unsigned short*)(base + 18350080);   //   524,288
    unsigned short* We_f    = (unsigned short*)(base + 18874368);   //   524,288
    unsigned short* lse_f   = (unsigned short*)(base + 19398656);   //   524,288
    float*          S12     = (float*)(base + 19922944);            //    32,768

    fused_cast<<<1408, 256, 0, stream>>>(W, dec, enc, Wd_f, We_f, dec_f,
                                         enc_f, encT_f, S12);
    gemm1<<<576, 256, 0, stream>>>(enc_f, dec_f, Wd_f, We_f, bias, enc,
                                   part_bf, uv_f, S12);
    lse_k<<<256, 256, 0, stream>>>(uv_f, lse_f);
    final_k<<<256, 256, 0, stream>>>(lse_f, encT_f, part_bf, bias, S12, out);
}